// Round 12
// baseline (932.309 us; speedup 1.0000x reference)
//
#include <hip/hip_runtime.h>
#include <hip/hip_bf16.h>
#include <math.h>

typedef __attribute__((ext_vector_type(8))) short bf16x8;
typedef __attribute__((ext_vector_type(4))) float f32x4;
typedef __attribute__((ext_vector_type(16))) float f32x16;
typedef __attribute__((ext_vector_type(4))) unsigned u32x4;

__device__ __forceinline__ float silu_f(float x){
  return x * __builtin_amdgcn_rcpf(1.f + __expf(-x));
}

// fp32 -> bf16 (round-to-nearest-even, finite inputs)
__device__ __forceinline__ short f2bs(float x){
  unsigned u = __builtin_bit_cast(unsigned, x);
  unsigned r = (u + 0x7fffu + ((u >> 16) & 1u)) >> 16;
  return (short)r;
}

// ---------------- edge-index layout detect (int64 vs int32) ----------------
__global__ void k_detect(const int* __restrict__ ei, int E, int* __restrict__ flag){
  __shared__ int nz;
  if (threadIdx.x==0) nz = 0;
  __syncthreads();
  int lim = E < 4096 ? E : 4096;
  int c = 0;
  for (int e = threadIdx.x; e < lim; e += blockDim.x)
    if (ei[2*e+1] != 0) c++;
  if (c) atomicAdd(&nz, c);
  __syncthreads();
  if (threadIdx.x==0) *flag = (nz==0) ? 1 : 0;   // 1 => int64 little-endian
}

__global__ __launch_bounds__(256) void k_deg(const int* __restrict__ ei, int E,
                                             const int* __restrict__ flag, int* __restrict__ deg){
  int e = blockIdx.x*blockDim.x + threadIdx.x;
  if (e >= E) return;
  int d = (*flag) ? ei[2*(E+e)] : ei[E+e];
  atomicAdd(&deg[d], 1);
}

// ---------------- exclusive scan over N (2-level) ----------------
__global__ __launch_bounds__(256) void k_scan1(const int* __restrict__ deg, int* __restrict__ offs,
                                               int* __restrict__ bsum, int n){
  __shared__ int sh[256];
  int i = blockIdx.x*256 + threadIdx.x;
  int v = (i < n) ? deg[i] : 0;
  sh[threadIdx.x] = v;
  __syncthreads();
  for (int off=1; off<256; off<<=1){
    int t = (threadIdx.x >= off) ? sh[threadIdx.x-off] : 0;
    __syncthreads();
    sh[threadIdx.x] += t;
    __syncthreads();
  }
  if (i < n) offs[i] = sh[threadIdx.x] - v;
  if (threadIdx.x == 255) bsum[blockIdx.x] = sh[255];
}

__global__ __launch_bounds__(512) void k_scan2(int* __restrict__ bsum, int nb){
  __shared__ int sh[512];
  int v = (threadIdx.x < nb) ? bsum[threadIdx.x] : 0;
  sh[threadIdx.x] = v;
  __syncthreads();
  for (int off=1; off<512; off<<=1){
    int t = (threadIdx.x >= off) ? sh[threadIdx.x-off] : 0;
    __syncthreads();
    sh[threadIdx.x] += t;
    __syncthreads();
  }
  if (threadIdx.x < nb) bsum[threadIdx.x] = sh[threadIdx.x] - v;
}

__global__ __launch_bounds__(256) void k_scan3(int* __restrict__ offs, const int* __restrict__ bsum,
                                               int* __restrict__ cursor, int n){
  int i = blockIdx.x*256 + threadIdx.x;
  if (i >= n) return;
  int o = offs[i] + bsum[i>>8];
  offs[i] = o;
  cursor[i] = o;
}

// ---------------- per-node precompute: nrec = {mx,my,mz,|m|, nt0,nt1,0,0}, h0 ----------------
__global__ __launch_bounds__(256) void k_node_pre(const float* __restrict__ x,
                                                  const float* __restrict__ inw, const float* __restrict__ inb,
                                                  float4* __restrict__ nrec,
                                                  float* __restrict__ h, int n){
  int half = threadIdx.x >> 7;
  int k = threadIdx.x & 127;
  int i = blockIdx.x*2 + half;
  if (i >= n) return;
  float nt0 = x[i*5+0], nt1 = x[i*5+1];
  float sx = x[i*5+2], sy = x[i*5+3], sz = x[i*5+4];
  float nrm = sqrtf(sx*sx + sy*sy + sz*sz);
  float d = fmaxf(nrm, 1e-12f);
  float mx = sx/d, my = sy/d, mz = sz/d;
  float rn = sqrtf(mx*mx + my*my + mz*mz);
  float v = nt0*inw[k] + nt1*inw[128+k] + rn*inw[256+k] + inb[k];
  h[i*128 + k] = silu_f(v);
  if (k == 0){
    nrec[(size_t)i*2]   = make_float4(mx, my, mz, rn);
    nrec[(size_t)i*2+1] = make_float4(nt0, nt1, 0.f, 0.f);
  }
}

// ---------------- scatter edges into dst-sorted order (32 B bf16 rows) ----------------
// scE row (16 bf16, 32 B): [|m_i|,|m_j|,mi·mj,mi·u,mj·u,dist,nti0,nti1,ntj0,ntj1, 1.0, 0...]
__global__ __launch_bounds__(256) void k_scatter(const int* __restrict__ ei, int E,
                                                 const int* __restrict__ flag,
                                                 const float* __restrict__ eattr,
                                                 const float4* __restrict__ nrec,
                                                 int* __restrict__ cursor,
                                                 int* __restrict__ srcS, ushort* __restrict__ scE){
  int e = blockIdx.x*blockDim.x + threadIdx.x;
  if (e >= E) return;
  int i64 = *flag;
  int s = i64 ? ei[2*e]       : ei[e];
  int d = i64 ? ei[2*(E+e)]   : ei[E+e];
  float4 ea = *(const float4*)(eattr + (size_t)e*4);
  float4 mi  = nrec[(size_t)d*2];
  float4 nti = nrec[(size_t)d*2+1];
  float4 mj  = nrec[(size_t)s*2];
  float4 ntj = nrec[(size_t)s*2+1];
  __align__(16) ushort row[16];
  row[0] = (ushort)f2bs(mi.w);
  row[1] = (ushort)f2bs(mj.w);
  row[2] = (ushort)f2bs(mi.x*mj.x + mi.y*mj.y + mi.z*mj.z);
  row[3] = (ushort)f2bs(mi.x*ea.x + mi.y*ea.y + mi.z*ea.z);
  row[4] = (ushort)f2bs(mj.x*ea.x + mj.y*ea.y + mj.z*ea.z);
  row[5] = (ushort)f2bs(ea.w);
  row[6] = (ushort)f2bs(nti.x);
  row[7] = (ushort)f2bs(nti.y);
  row[8] = (ushort)f2bs(ntj.x);
  row[9] = (ushort)f2bs(ntj.y);
  row[10]= 0x3F80;  // 1.0 bf16 (bias rides as B's k=10 row)
  row[11]=0; row[12]=0; row[13]=0; row[14]=0; row[15]=0;
  int pos = atomicAdd(&cursor[d], 1);
  srcS[pos] = s;
  u32x4* dstp = (u32x4*)(scE + (size_t)pos*16);
  dstp[0] = *(u32x4*)row;
  dstp[1] = *(u32x4*)(row + 8);
}

// ---------------- pack weights to MFMA B-fragment-major bf16 ----------------
// 16x16x32 B-frag: lane L holds B[k=(L>>4)*8+e][n=L&15]; tile index = c*8+t
// blocks 416..427: ew1 packed for 32x32x16 (K16, bias in k=10): lane L holds
// B[k=(L>>5)*8+j][col=t*32+(L&31)]
__global__ __launch_bounds__(64) void k_pack(const float* __restrict__ ew2, const float* __restrict__ nw1,
                                             const float* __restrict__ nw2, const float* __restrict__ ow1,
                                             const float* __restrict__ ew1, const float* __restrict__ eb1,
                                             short* __restrict__ p_ew2, short* __restrict__ p_nw1,
                                             short* __restrict__ p_nw2, short* __restrict__ p_ow1,
                                             short* __restrict__ p_ew1b){
  int b = blockIdx.x;
  int L = threadIdx.x;
  if (b >= 416){
    int tile = b - 416;          // 0..11
    int l = tile >> 2, t = tile & 3;
    int col = t*32 + (L & 31);
    int kb  = (L >> 5) << 3;
    __align__(16) short tmp[8];
    #pragma unroll
    for (int j=0;j<8;j++){
      int k = kb + j;
      float v = 0.f;
      if (k < 10)       v = ew1[(size_t)l*1280 + (size_t)k*128 + col];
      else if (k == 10) v = eb1[(size_t)l*128 + col];
      tmp[j] = f2bs(v);
    }
    *(bf16x8*)(p_ew1b + ((size_t)(l*4+t)*64 + L)*8) = *(bf16x8*)tmp;
    return;
  }
  const float* src; short* dst; int tile;
  if (b < 96){        int l = b>>5;              tile = b & 31; src = ew2 + (size_t)l*16384; dst = p_ew2 + (size_t)l*16384; }
  else if (b < 288){  int l = (b-96)>>6;         tile = (b-96) & 63; src = nw1 + (size_t)l*32768; dst = p_nw1 + (size_t)l*32768; }
  else if (b < 384){  int l = (b-288)>>5;        tile = (b-288) & 31; src = nw2 + (size_t)l*16384; dst = p_nw2 + (size_t)l*16384; }
  else {                                          tile = b - 384; src = ow1; dst = p_ow1; }
  int c = tile >> 3, t = tile & 7;
  int kb  = c*32 + ((L>>4)<<3);
  int col = t*16 + (L&15);
  __align__(16) short tmp[8];
  #pragma unroll
  for (int e=0;e<8;e++) tmp[e] = f2bs(src[(size_t)(kb+e)*128 + col]);
  *(bf16x8*)(dst + ((size_t)tile*64 + L)*8) = *(bf16x8*)tmp;
}

// ---------------- edge MLP hidden sums, ALL 3 layers, ONE scE pass ----------------
// 32 edges/group via mfma_f32_32x32x16_bf16 (K16 >= 11 used).
// A[m=lane&31][k=(lane>>5)*8+j]: each scE 32B row splits across the two lane-halves
// -> every lane loads 16B of real data. C/D: col=lane&31, row=(reg&3)+8*(reg>>2)+4*(lane>>5).
// Padded edges -> zero A-row -> silu(0)=0 -> no masking.
__global__ __launch_bounds__(256) void k_edge3(
    const ushort* __restrict__ scE,
    const int* __restrict__ offs, const int* __restrict__ deg,
    const short* __restrict__ p_ew1b,
    ushort* __restrict__ A, int n, size_t lstride){
  int wv = threadIdx.x >> 6, lane = threadIdx.x & 63;
  int i = blockIdx.x*4 + wv;
  if (i >= n) return;
  int half = lane >> 5, lr = lane & 31;
  int p0 = __builtin_amdgcn_readfirstlane(offs[i]);
  int dg = __builtin_amdgcn_readfirstlane(deg[i]);
  float s[3][4];
  #pragma unroll
  for (int l=0;l<3;l++){ s[l][0]=0.f; s[l][1]=0.f; s[l][2]=0.f; s[l][3]=0.f; }
  f32x16 zf;
  #pragma unroll
  for (int r=0;r<16;r++) zf[r] = 0.f;
  const u32x4 z4 = {0u,0u,0u,0u};
  for (int g=0; g<dg; g+=32){
    int e = g + lr;
    u32x4 d4 = z4;
    if (e < dg)
      d4 = *(const u32x4*)(scE + ((size_t)(p0+e))*16 + half*8);
    bf16x8 af = __builtin_bit_cast(bf16x8, d4);
    #pragma unroll
    for (int l=0;l<3;l++){
      #pragma unroll
      for (int t=0;t<4;t++){
        bf16x8 bf = *(const bf16x8*)(p_ew1b + ((size_t)(l*4+t)*64 + lane)*8);
        f32x16 acc = __builtin_amdgcn_mfma_f32_32x32x16_bf16(af, bf, zf, 0, 0, 0);
        float ss = 0.f;
        #pragma unroll
        for (int r=0;r<16;r++) ss += silu_f(acc[r]);
        s[l][t] += ss;
      }
    }
  }
  #pragma unroll
  for (int l=0;l<3;l++)
    #pragma unroll
    for (int t=0;t<4;t++)
      s[l][t] += __shfl_xor(s[l][t], 32, 64);
  if (half == 0){
    #pragma unroll
    for (int l=0;l<3;l++)
      #pragma unroll
      for (int t=0;t<4;t++)
        A[lstride*l + (size_t)i*128 + t*32 + lr] = (ushort)f2bs(s[l][t]);
  }
}

// ---------------- MFMA wave GEMM: 16 rows x 128 cols, K = kchunks*32 ----------------
__device__ __forceinline__ void wave_gemm(const short* __restrict__ sIn, const short* __restrict__ pw,
                                          int lane, int kchunks, f32x4 acc[8]){
  for (int c=0;c<kchunks;c++){
    bf16x8 af = *(const bf16x8*)(sIn + (lane&15)*136 + c*32 + ((lane>>4)<<3));
    const short* pB = pw + (size_t)c*4096 + (size_t)lane*8;
    #pragma unroll
    for (int t=0;t<8;t++){
      bf16x8 bf = *(const bf16x8*)(pB + t*512);
      acc[t] = __builtin_amdgcn_mfma_f32_16x16x32_bf16(af, bf, acc[t], 0, 0, 0);
    }
  }
}

// ---------------- fused per-layer node update (MFMA); LAST also computes output head ----------------
template<bool LAST>
__global__ __launch_bounds__(256) void k_layer(
    const ushort* __restrict__ A, float* __restrict__ h,
    const short* __restrict__ p_ew2, const float* __restrict__ eb2,
    const short* __restrict__ p_nw1, const float* __restrict__ nb1,
    const short* __restrict__ p_nw2, const float* __restrict__ nb2,
    const int* __restrict__ deg,
    const short* __restrict__ p_ow1, const float* __restrict__ ob1,
    const float* __restrict__ ow2, const float* __restrict__ ob2,
    float* __restrict__ wout, int n){
  __shared__ __align__(16) short sA[64*136];
  __shared__ __align__(16) short sH[64*136];
  __shared__ __align__(16) short sG[64*136];
  int tid = threadIdx.x;
  int lane = tid & 63, wave = tid >> 6;
  int row0 = blockIdx.x*64;

  #pragma unroll
  for (int q=0;q<8;q++){
    int id = tid + q*256;
    int r = id >> 5;
    int cq = (id & 31) << 2;
    int row = row0 + r;
    ushort4 va = make_ushort4(0,0,0,0);
    float4 vh = make_float4(0.f,0.f,0.f,0.f);
    if (row < n){
      va = *(const ushort4*)(A + (size_t)row*128 + cq);
      vh = *(const float4*)(h + (size_t)row*128 + cq);
    }
    *(ushort4*)&sA[r*136 + cq] = va;
    short4 hs; hs.x = f2bs(vh.x); hs.y = f2bs(vh.y); hs.z = f2bs(vh.z); hs.w = f2bs(vh.w);
    *(short4*)&sH[r*136 + cq] = hs;
  }
  __syncthreads();

  const short* sInA = sA + wave*16*136;
  const short* sInH = sH + wave*16*136;
  const short* sInG = sG + wave*16*136;
  int lr = lane & 15;
  int rbase = wave*16 + ((lane>>4)<<2);

  f32x4 acc[8];
  const f32x4 zf = {0.f,0.f,0.f,0.f};

  // GEMM-A: aggr = A @ ew2 + deg*eb2 -> sG
  #pragma unroll
  for (int t=0;t<8;t++) acc[t] = zf;
  wave_gemm(sInA, p_ew2, lane, 4, acc);
  {
    float dd[4];
    #pragma unroll
    for (int r=0;r<4;r++){
      int row = row0 + rbase + r;
      dd[r] = (row < n) ? (float)deg[row] : 0.f;
    }
    #pragma unroll
    for (int t=0;t<8;t++){
      int col = t*16 + lr;
      float bv = eb2[col];
      #pragma unroll
      for (int r=0;r<4;r++)
        sG[(rbase+r)*136 + col] = f2bs(acc[t][r] + dd[r]*bv);
    }
  }
  __syncthreads();

  // GEMM-B: u = silu([h|aggr] @ nw1 + nb1) -> sA
  #pragma unroll
  for (int t=0;t<8;t++) acc[t] = zf;
  wave_gemm(sInH, p_nw1,         lane, 4, acc);
  wave_gemm(sInG, p_nw1 + 16384, lane, 4, acc);
  __syncthreads();
  {
    #pragma unroll
    for (int t=0;t<8;t++){
      int col = t*16 + lr;
      float bv = nb1[col];
      #pragma unroll
      for (int r=0;r<4;r++)
        sA[(rbase+r)*136 + col] = f2bs(silu_f(acc[t][r] + bv));
    }
  }
  __syncthreads();

  // GEMM-C: h_new = h + u @ nw2 + nb2
  #pragma unroll
  for (int t=0;t<8;t++) acc[t] = zf;
  wave_gemm(sInA, p_nw2, lane, 4, acc);
  {
    #pragma unroll
    for (int t=0;t<8;t++){
      int col = t*16 + lr;
      float bv = nb2[col];
      #pragma unroll
      for (int r=0;r<4;r++){
        int row = row0 + rbase + r;
        if (row < n){
          size_t idx = (size_t)row*128 + col;
          float hv = h[idx] + acc[t][r] + bv;
          if (LAST) sH[(rbase+r)*136 + col] = f2bs(hv);  // wave-private stripe
          else      h[idx] = hv;
        }
      }
    }
  }

  if (LAST){
    // head: wout = silu(h_new@ow1+ob1)·ow2 + ob2 (reads own stripe; no barrier needed)
    #pragma unroll
    for (int t=0;t<8;t++) acc[t] = zf;
    wave_gemm(sInH, p_ow1, lane, 4, acc);
    float p[4] = {0.f,0.f,0.f,0.f};
    #pragma unroll
    for (int t=0;t<8;t++){
      int col = t*16 + lr;
      float b1 = ob1[col], w2 = ow2[col];
      #pragma unroll
      for (int r=0;r<4;r++) p[r] += silu_f(acc[t][r] + b1)*w2;
    }
    #pragma unroll
    for (int m=1;m<16;m<<=1){
      #pragma unroll
      for (int r=0;r<4;r++) p[r] += __shfl_xor(p[r], m, 64);
    }
    if (lr == 0){
      float b = ob2[0];
      #pragma unroll
      for (int r=0;r<4;r++){
        int row = row0 + rbase + r;
        if (row < n) wout[row] = p[r] + b;
      }
    }
  }
}

// ---------------- b_field: quad (16 lanes) per node ----------------
__global__ __launch_bounds__(256) void k_bfield(const int* __restrict__ srcS,
                                                const float4* __restrict__ nrec,
                                                const float* __restrict__ wout, const int* __restrict__ offs,
                                                const int* __restrict__ deg, float* __restrict__ out, int n){
  int tid = threadIdx.x;
  int lr = tid & 15;
  int i = blockIdx.x*16 + (tid >> 4);
  if (i >= n) return;
  int p0 = offs[i], e = deg[i];
  float ax=0.f, ay=0.f, az=0.f;
  for (int q=lr; q<e; q+=16){
    int s = srcS[p0+q];
    float wg = wout[s];
    float4 sp = nrec[(size_t)s*2];
    ax += wg*sp.x; ay += wg*sp.y; az += wg*sp.z;
  }
  #pragma unroll
  for (int m=1;m<16;m<<=1){
    ax += __shfl_xor(ax, m, 64);
    ay += __shfl_xor(ay, m, 64);
    az += __shfl_xor(az, m, 64);
  }
  if (lr == 0){
    out[(size_t)i*3+0] = ax;
    out[(size_t)i*3+1] = ay;
    out[(size_t)i*3+2] = az;
  }
}

extern "C" void kernel_launch(void* const* d_in, const int* in_sizes, int n_in,
                              void* d_out, int out_size, void* d_ws, size_t ws_size,
                              hipStream_t stream){
  const float* x      = (const float*)d_in[0];
  const int*   ei     = (const int*)  d_in[1];
  const float* eattr  = (const float*)d_in[2];
  const float* in_w   = (const float*)d_in[3];
  const float* in_b   = (const float*)d_in[4];
  const float* ew1    = (const float*)d_in[5];
  const float* eb1    = (const float*)d_in[6];
  const float* ew2    = (const float*)d_in[7];
  const float* eb2    = (const float*)d_in[8];
  const float* nw1    = (const float*)d_in[9];
  const float* nb1    = (const float*)d_in[10];
  const float* nw2    = (const float*)d_in[11];
  const float* nb2    = (const float*)d_in[12];
  const float* ow1    = (const float*)d_in[13];
  const float* ob1    = (const float*)d_in[14];
  const float* ow2    = (const float*)d_in[15];
  const float* ob2    = (const float*)d_in[16];
  float* out = (float*)d_out;

  const int N = in_sizes[0] / 5;
  const int E = in_sizes[1] / 2;

  char* w = (char*)d_ws;
  size_t off = 0;
  auto alloc = [&](size_t bytes)->size_t{
    size_t o = off; off = (off + bytes + 255) & ~(size_t)255; return o;
  };
  size_t o_flag   = alloc(4);
  size_t o_deg    = alloc((size_t)N*4);
  size_t o_offs   = alloc((size_t)N*4);
  size_t o_cursor = alloc((size_t)N*4);
  size_t o_bsum   = alloc(512*4);
  size_t o_nrec   = alloc((size_t)N*32);
  size_t o_wout   = alloc((size_t)N*4);
  size_t o_h      = alloc((size_t)N*128*4);
  size_t o_A      = alloc((size_t)3*N*128*2);      // 3 layers, bf16
  size_t o_pew2   = alloc((size_t)3*128*128*2);
  size_t o_pnw1   = alloc((size_t)3*256*128*2);
  size_t o_pnw2   = alloc((size_t)3*128*128*2);
  size_t o_pow1   = alloc((size_t)128*128*2);
  size_t o_pew1b  = alloc((size_t)3*4*64*8*2);     // 32x32x16 B-frags
  size_t o_srcS   = alloc((size_t)E*4);
  size_t o_scE    = alloc((size_t)E*32);
  if (off > ws_size) return;

  int*    flag   = (int*)   (w + o_flag);
  int*    deg    = (int*)   (w + o_deg);
  int*    offs   = (int*)   (w + o_offs);
  int*    cursor = (int*)   (w + o_cursor);
  int*    bsum   = (int*)   (w + o_bsum);
  float4* nrec   = (float4*)(w + o_nrec);
  float*  wout   = (float*) (w + o_wout);
  float*  h      = (float*) (w + o_h);
  ushort* A      = (ushort*)(w + o_A);
  short*  p_ew2  = (short*) (w + o_pew2);
  short*  p_nw1  = (short*) (w + o_pnw1);
  short*  p_nw2  = (short*) (w + o_pnw2);
  short*  p_ow1  = (short*) (w + o_pow1);
  short*  p_ew1b = (short*) (w + o_pew1b);
  int*    srcS   = (int*)   (w + o_srcS);
  ushort* scE    = (ushort*)(w + o_scE);

  (void)hipMemsetAsync(deg, 0, (size_t)N*4, stream);

  const int nb = (N + 255) / 256;
  const size_t lstride = (size_t)N*128;

  k_detect<<<1, 256, 0, stream>>>(ei, E, flag);
  k_deg<<<(E+255)/256, 256, 0, stream>>>(ei, E, flag, deg);
  k_scan1<<<nb, 256, 0, stream>>>(deg, offs, bsum, N);
  k_scan2<<<1, 512, 0, stream>>>(bsum, nb);
  k_scan3<<<nb, 256, 0, stream>>>(offs, bsum, cursor, N);
  k_node_pre<<<(N+1)/2, 256, 0, stream>>>(x, in_w, in_b, nrec, h, N);
  k_scatter<<<(E+255)/256, 256, 0, stream>>>(ei, E, flag, eattr, nrec, cursor, srcS, scE);
  k_pack<<<428, 64, 0, stream>>>(ew2, nw1, nw2, ow1, ew1, eb1,
                                 p_ew2, p_nw1, p_nw2, p_ow1, p_ew1b);

  // all 3 layers' edge-hidden sums in ONE pass (32-edge groups, 32x32x16 MFMA)
  k_edge3<<<(N+3)/4, 256, 0, stream>>>(scE, offs, deg, p_ew1b, A, N, lstride);

  const int gb = (N + 63) / 64;
  for (int l=0; l<2; ++l){
    k_layer<false><<<gb, 256, 0, stream>>>(A + lstride*l, h,
                                    p_ew2 + (size_t)l*16384, eb2 + (size_t)l*128,
                                    p_nw1 + (size_t)l*32768, nb1 + (size_t)l*128,
                                    p_nw2 + (size_t)l*16384, nb2 + (size_t)l*128,
                                    deg, nullptr, nullptr, nullptr, nullptr, nullptr, N);
  }
  k_layer<true><<<gb, 256, 0, stream>>>(A + lstride*2, h,
                                  p_ew2 + (size_t)2*16384, eb2 + (size_t)2*128,
                                  p_nw1 + (size_t)2*32768, nb1 + (size_t)2*128,
                                  p_nw2 + (size_t)2*16384, nb2 + (size_t)2*128,
                                  deg, p_ow1, ob1, ow2, ob2, wout, N);

  k_bfield<<<(N+15)/16, 256, 0, stream>>>(srcS, nrec, wout, offs, deg, out, N);
}

// Round 13
// 867.733 us; speedup vs baseline: 1.0744x; 1.0744x over previous
//
#include <hip/hip_runtime.h>
#include <hip/hip_bf16.h>
#include <math.h>

typedef __attribute__((ext_vector_type(8))) short bf16x8;
typedef __attribute__((ext_vector_type(4))) float f32x4;
typedef __attribute__((ext_vector_type(4))) unsigned u32x4;

__device__ __forceinline__ float silu_f(float x){
  return x * __builtin_amdgcn_rcpf(1.f + __expf(-x));
}

// fp32 -> bf16 (round-to-nearest-even, finite inputs)
__device__ __forceinline__ short f2bs(float x){
  unsigned u = __builtin_bit_cast(unsigned, x);
  unsigned r = (u + 0x7fffu + ((u >> 16) & 1u)) >> 16;
  return (short)r;
}

// ---------------- edge-index layout detect (int64 vs int32) ----------------
__global__ void k_detect(const int* __restrict__ ei, int E, int* __restrict__ flag){
  __shared__ int nz;
  if (threadIdx.x==0) nz = 0;
  __syncthreads();
  int lim = E < 4096 ? E : 4096;
  int c = 0;
  for (int e = threadIdx.x; e < lim; e += blockDim.x)
    if (ei[2*e+1] != 0) c++;
  if (c) atomicAdd(&nz, c);
  __syncthreads();
  if (threadIdx.x==0) *flag = (nz==0) ? 1 : 0;   // 1 => int64 little-endian
}

__global__ __launch_bounds__(256) void k_deg(const int* __restrict__ ei, int E,
                                             const int* __restrict__ flag, int* __restrict__ deg){
  int e = blockIdx.x*blockDim.x + threadIdx.x;
  if (e >= E) return;
  int d = (*flag) ? ei[2*(E+e)] : ei[E+e];
  atomicAdd(&deg[d], 1);
}

// ---------------- exclusive scan over N (2-level) ----------------
__global__ __launch_bounds__(256) void k_scan1(const int* __restrict__ deg, int* __restrict__ offs,
                                               int* __restrict__ bsum, int n){
  __shared__ int sh[256];
  int i = blockIdx.x*256 + threadIdx.x;
  int v = (i < n) ? deg[i] : 0;
  sh[threadIdx.x] = v;
  __syncthreads();
  for (int off=1; off<256; off<<=1){
    int t = (threadIdx.x >= off) ? sh[threadIdx.x-off] : 0;
    __syncthreads();
    sh[threadIdx.x] += t;
    __syncthreads();
  }
  if (i < n) offs[i] = sh[threadIdx.x] - v;
  if (threadIdx.x == 255) bsum[blockIdx.x] = sh[255];
}

__global__ __launch_bounds__(512) void k_scan2(int* __restrict__ bsum, int nb){
  __shared__ int sh[512];
  int v = (threadIdx.x < nb) ? bsum[threadIdx.x] : 0;
  sh[threadIdx.x] = v;
  __syncthreads();
  for (int off=1; off<512; off<<=1){
    int t = (threadIdx.x >= off) ? sh[threadIdx.x-off] : 0;
    __syncthreads();
    sh[threadIdx.x] += t;
    __syncthreads();
  }
  if (threadIdx.x < nb) bsum[threadIdx.x] = sh[threadIdx.x] - v;
}

__global__ __launch_bounds__(256) void k_scan3(int* __restrict__ offs, const int* __restrict__ bsum,
                                               int* __restrict__ cursor, int n){
  int i = blockIdx.x*256 + threadIdx.x;
  if (i >= n) return;
  int o = offs[i] + bsum[i>>8];
  offs[i] = o;
  cursor[i] = o;
}

// ---------------- per-node precompute: nrec = {mx,my,mz,|m|, nt0,nt1,0,0}, h0 ----------------
__global__ __launch_bounds__(256) void k_node_pre(const float* __restrict__ x,
                                                  const float* __restrict__ inw, const float* __restrict__ inb,
                                                  float4* __restrict__ nrec,
                                                  float* __restrict__ h, int n){
  int half = threadIdx.x >> 7;
  int k = threadIdx.x & 127;
  int i = blockIdx.x*2 + half;
  if (i >= n) return;
  float nt0 = x[i*5+0], nt1 = x[i*5+1];
  float sx = x[i*5+2], sy = x[i*5+3], sz = x[i*5+4];
  float nrm = sqrtf(sx*sx + sy*sy + sz*sz);
  float d = fmaxf(nrm, 1e-12f);
  float mx = sx/d, my = sy/d, mz = sz/d;
  float rn = sqrtf(mx*mx + my*my + mz*mz);
  float v = nt0*inw[k] + nt1*inw[128+k] + rn*inw[256+k] + inb[k];
  h[i*128 + k] = silu_f(v);
  if (k == 0){
    nrec[(size_t)i*2]   = make_float4(mx, my, mz, rn);
    nrec[(size_t)i*2+1] = make_float4(nt0, nt1, 0.f, 0.f);
  }
}

// ---------------- scatter edges into dst-sorted order (32 B bf16 rows) ----------------
// scE row (16 bf16, 32 B): [|m_i|,|m_j|,mi·mj,mi·u,mj·u,dist,nti0,nti1,ntj0,ntj1, 1.0, 0...]
__global__ __launch_bounds__(256) void k_scatter(const int* __restrict__ ei, int E,
                                                 const int* __restrict__ flag,
                                                 const float* __restrict__ eattr,
                                                 const float4* __restrict__ nrec,
                                                 int* __restrict__ cursor,
                                                 int* __restrict__ srcS, ushort* __restrict__ scE){
  int e = blockIdx.x*blockDim.x + threadIdx.x;
  if (e >= E) return;
  int i64 = *flag;
  int s = i64 ? ei[2*e]       : ei[e];
  int d = i64 ? ei[2*(E+e)]   : ei[E+e];
  float4 ea = *(const float4*)(eattr + (size_t)e*4);
  float4 mi  = nrec[(size_t)d*2];
  float4 nti = nrec[(size_t)d*2+1];
  float4 mj  = nrec[(size_t)s*2];
  float4 ntj = nrec[(size_t)s*2+1];
  __align__(16) ushort row[16];
  row[0] = (ushort)f2bs(mi.w);
  row[1] = (ushort)f2bs(mj.w);
  row[2] = (ushort)f2bs(mi.x*mj.x + mi.y*mj.y + mi.z*mj.z);
  row[3] = (ushort)f2bs(mi.x*ea.x + mi.y*ea.y + mi.z*ea.z);
  row[4] = (ushort)f2bs(mj.x*ea.x + mj.y*ea.y + mj.z*ea.z);
  row[5] = (ushort)f2bs(ea.w);
  row[6] = (ushort)f2bs(nti.x);
  row[7] = (ushort)f2bs(nti.y);
  row[8] = (ushort)f2bs(ntj.x);
  row[9] = (ushort)f2bs(ntj.y);
  row[10]= 0x3F80;  // 1.0 bf16 (bias rides as B's k=10 row)
  row[11]=0; row[12]=0; row[13]=0; row[14]=0; row[15]=0;
  int pos = atomicAdd(&cursor[d], 1);
  srcS[pos] = s;
  u32x4* dstp = (u32x4*)(scE + (size_t)pos*16);
  dstp[0] = *(u32x4*)row;
  dstp[1] = *(u32x4*)(row + 8);
}

// ---------------- pack weights to MFMA B-fragment-major bf16 ----------------
// B-frag (16x16x32): lane L holds B[k=(L>>4)*8+e][n=L&15]; tile index = c*8+t
// blocks 416..439: ew1 (10x128, +bias row k=10, zero-pad to K=32)
__global__ __launch_bounds__(64) void k_pack(const float* __restrict__ ew2, const float* __restrict__ nw1,
                                             const float* __restrict__ nw2, const float* __restrict__ ow1,
                                             const float* __restrict__ ew1, const float* __restrict__ eb1,
                                             short* __restrict__ p_ew2, short* __restrict__ p_nw1,
                                             short* __restrict__ p_nw2, short* __restrict__ p_ow1,
                                             short* __restrict__ p_ew1){
  int b = blockIdx.x;
  int L = threadIdx.x;
  if (b >= 416){
    int tile = b - 416;          // 0..23
    int l = tile >> 3, t = tile & 7;
    int col = t*16 + (L & 15);
    int kb  = (L >> 4) << 3;
    __align__(16) short tmp[8];
    #pragma unroll
    for (int e=0;e<8;e++){
      int k = kb + e;
      float v = 0.f;
      if (k < 10)       v = ew1[(size_t)l*1280 + (size_t)k*128 + col];
      else if (k == 10) v = eb1[(size_t)l*128 + col];
      tmp[e] = f2bs(v);
    }
    *(bf16x8*)(p_ew1 + (size_t)l*4096 + t*512 + L*8) = *(bf16x8*)tmp;
    return;
  }
  const float* src; short* dst; int tile;
  if (b < 96){        int l = b>>5;              tile = b & 31; src = ew2 + (size_t)l*16384; dst = p_ew2 + (size_t)l*16384; }
  else if (b < 288){  int l = (b-96)>>6;         tile = (b-96) & 63; src = nw1 + (size_t)l*32768; dst = p_nw1 + (size_t)l*32768; }
  else if (b < 384){  int l = (b-288)>>5;        tile = (b-288) & 31; src = nw2 + (size_t)l*16384; dst = p_nw2 + (size_t)l*16384; }
  else {                                          tile = b - 384; src = ow1; dst = p_ow1; }
  int c = tile >> 3, t = tile & 7;
  int kb  = c*32 + ((L>>4)<<3);
  int col = t*16 + (L&15);
  __align__(16) short tmp[8];
  #pragma unroll
  for (int e=0;e<8;e++) tmp[e] = f2bs(src[(size_t)(kb+e)*128 + col]);
  *(bf16x8*)(dst + ((size_t)tile*64 + L)*8) = *(bf16x8*)tmp;
}

// ---------------- edge MLP hidden sums, ALL 3 layers, ONE scE pass (wave per node) ----------------
// 16-edge groups via 16x16x32; B-frags reloaded per layer per group from L1 (24 KB).
// Padded edges -> zero A-row -> silu(0)=0 -> no masking.
__global__ __launch_bounds__(256) void k_edge3(
    const ushort* __restrict__ scE,
    const int* __restrict__ offs, const int* __restrict__ deg,
    const short* __restrict__ p_ew1,
    ushort* __restrict__ A, int n, size_t lstride){
  int wv = threadIdx.x >> 6, lane = threadIdx.x & 63;
  int i = blockIdx.x*4 + wv;
  if (i >= n) return;
  int quad = lane >> 4, lr = lane & 15;
  int p0 = __builtin_amdgcn_readfirstlane(offs[i]);
  int dg = __builtin_amdgcn_readfirstlane(deg[i]);
  float s[3][8];
  #pragma unroll
  for (int l=0;l<3;l++)
    #pragma unroll
    for (int t=0;t<8;t++) s[l][t] = 0.f;
  const f32x4 zf = {0.f,0.f,0.f,0.f};
  const u32x4 z4 = {0u,0u,0u,0u};
  for (int g=0; g<dg; g+=16){
    int e = g + lr;
    u32x4 d4 = z4;
    if (quad < 2 && e < dg)
      d4 = *(const u32x4*)(scE + ((size_t)(p0+e))*16 + quad*8);
    bf16x8 af = __builtin_bit_cast(bf16x8, d4);
    #pragma unroll
    for (int l=0;l<3;l++){
      const short* pB = p_ew1 + (size_t)l*4096 + (size_t)lane*8;
      #pragma unroll
      for (int t=0;t<8;t++){
        bf16x8 bf = *(const bf16x8*)(pB + t*512);
        f32x4 acc = __builtin_amdgcn_mfma_f32_16x16x32_bf16(af, bf, zf, 0, 0, 0);
        s[l][t] += silu_f(acc[0]) + silu_f(acc[1]) + silu_f(acc[2]) + silu_f(acc[3]);
      }
    }
  }
  #pragma unroll
  for (int l=0;l<3;l++)
    #pragma unroll
    for (int t=0;t<8;t++){
      s[l][t] += __shfl_xor(s[l][t], 16, 64);
      s[l][t] += __shfl_xor(s[l][t], 32, 64);
    }
  if (quad == 0){
    #pragma unroll
    for (int l=0;l<3;l++)
      #pragma unroll
      for (int t=0;t<8;t++)
        A[lstride*l + (size_t)i*128 + t*16 + lr] = (ushort)f2bs(s[l][t]);
  }
}

// ---------------- MFMA wave GEMM: 16 rows x 128 cols, K = kchunks*32 ----------------
__device__ __forceinline__ void wave_gemm(const short* __restrict__ sIn, const short* __restrict__ pw,
                                          int lane, int kchunks, f32x4 acc[8]){
  for (int c=0;c<kchunks;c++){
    bf16x8 af = *(const bf16x8*)(sIn + (lane&15)*136 + c*32 + ((lane>>4)<<3));
    const short* pB = pw + (size_t)c*4096 + (size_t)lane*8;
    #pragma unroll
    for (int t=0;t<8;t++){
      bf16x8 bf = *(const bf16x8*)(pB + t*512);
      acc[t] = __builtin_amdgcn_mfma_f32_16x16x32_bf16(af, bf, acc[t], 0, 0, 0);
    }
  }
}

// ---------------- fused per-layer node update (MFMA); LAST also computes head + wspin ----------------
template<bool LAST>
__global__ __launch_bounds__(256) void k_layer(
    const ushort* __restrict__ A, float* __restrict__ h,
    const short* __restrict__ p_ew2, const float* __restrict__ eb2,
    const short* __restrict__ p_nw1, const float* __restrict__ nb1,
    const short* __restrict__ p_nw2, const float* __restrict__ nb2,
    const int* __restrict__ deg,
    const short* __restrict__ p_ow1, const float* __restrict__ ob1,
    const float* __restrict__ ow2, const float* __restrict__ ob2,
    const float4* __restrict__ nrec, float4* __restrict__ wspin, int n){
  __shared__ __align__(16) short sA[64*136];
  __shared__ __align__(16) short sH[64*136];
  __shared__ __align__(16) short sG[64*136];
  int tid = threadIdx.x;
  int lane = tid & 63, wave = tid >> 6;
  int row0 = blockIdx.x*64;

  #pragma unroll
  for (int q=0;q<8;q++){
    int id = tid + q*256;
    int r = id >> 5;
    int cq = (id & 31) << 2;
    int row = row0 + r;
    ushort4 va = make_ushort4(0,0,0,0);
    float4 vh = make_float4(0.f,0.f,0.f,0.f);
    if (row < n){
      va = *(const ushort4*)(A + (size_t)row*128 + cq);
      vh = *(const float4*)(h + (size_t)row*128 + cq);
    }
    *(ushort4*)&sA[r*136 + cq] = va;
    short4 hs; hs.x = f2bs(vh.x); hs.y = f2bs(vh.y); hs.z = f2bs(vh.z); hs.w = f2bs(vh.w);
    *(short4*)&sH[r*136 + cq] = hs;
  }
  __syncthreads();

  const short* sInA = sA + wave*16*136;
  const short* sInH = sH + wave*16*136;
  const short* sInG = sG + wave*16*136;
  int lr = lane & 15;
  int rbase = wave*16 + ((lane>>4)<<2);

  f32x4 acc[8];
  const f32x4 zf = {0.f,0.f,0.f,0.f};

  // GEMM-A: aggr = A @ ew2 + deg*eb2 -> sG
  #pragma unroll
  for (int t=0;t<8;t++) acc[t] = zf;
  wave_gemm(sInA, p_ew2, lane, 4, acc);
  {
    float dd[4];
    #pragma unroll
    for (int r=0;r<4;r++){
      int row = row0 + rbase + r;
      dd[r] = (row < n) ? (float)deg[row] : 0.f;
    }
    #pragma unroll
    for (int t=0;t<8;t++){
      int col = t*16 + lr;
      float bv = eb2[col];
      #pragma unroll
      for (int r=0;r<4;r++)
        sG[(rbase+r)*136 + col] = f2bs(acc[t][r] + dd[r]*bv);
    }
  }
  __syncthreads();

  // GEMM-B: u = silu([h|aggr] @ nw1 + nb1) -> sA
  #pragma unroll
  for (int t=0;t<8;t++) acc[t] = zf;
  wave_gemm(sInH, p_nw1,         lane, 4, acc);
  wave_gemm(sInG, p_nw1 + 16384, lane, 4, acc);
  __syncthreads();
  {
    #pragma unroll
    for (int t=0;t<8;t++){
      int col = t*16 + lr;
      float bv = nb1[col];
      #pragma unroll
      for (int r=0;r<4;r++)
        sA[(rbase+r)*136 + col] = f2bs(silu_f(acc[t][r] + bv));
    }
  }
  __syncthreads();

  // GEMM-C: h_new = h + u @ nw2 + nb2
  #pragma unroll
  for (int t=0;t<8;t++) acc[t] = zf;
  wave_gemm(sInA, p_nw2, lane, 4, acc);
  {
    #pragma unroll
    for (int t=0;t<8;t++){
      int col = t*16 + lr;
      float bv = nb2[col];
      #pragma unroll
      for (int r=0;r<4;r++){
        int row = row0 + rbase + r;
        if (row < n){
          size_t idx = (size_t)row*128 + col;
          float hv = h[idx] + acc[t][r] + bv;
          if (LAST) sH[(rbase+r)*136 + col] = f2bs(hv);  // wave-private stripe
          else      h[idx] = hv;
        }
      }
    }
  }

  if (LAST){
    // head: w = silu(h_new@ow1+ob1)·ow2 + ob2 ; wspin[row] = w * spin[row]
    #pragma unroll
    for (int t=0;t<8;t++) acc[t] = zf;
    wave_gemm(sInH, p_ow1, lane, 4, acc);
    float p[4] = {0.f,0.f,0.f,0.f};
    #pragma unroll
    for (int t=0;t<8;t++){
      int col = t*16 + lr;
      float b1 = ob1[col], w2 = ow2[col];
      #pragma unroll
      for (int r=0;r<4;r++) p[r] += silu_f(acc[t][r] + b1)*w2;
    }
    #pragma unroll
    for (int m=1;m<16;m<<=1){
      #pragma unroll
      for (int r=0;r<4;r++) p[r] += __shfl_xor(p[r], m, 64);
    }
    if (lr == 0){
      float b = ob2[0];
      #pragma unroll
      for (int r=0;r<4;r++){
        int row = row0 + rbase + r;
        if (row < n){
          float wv = p[r] + b;
          float4 sp = nrec[(size_t)row*2];
          wspin[row] = make_float4(wv*sp.x, wv*sp.y, wv*sp.z, 0.f);
        }
      }
    }
  }
}

// ---------------- b_field: quad (16 lanes) per node, single wspin gather ----------------
__global__ __launch_bounds__(256) void k_bfield(const int* __restrict__ srcS,
                                                const float4* __restrict__ wspin,
                                                const int* __restrict__ offs,
                                                const int* __restrict__ deg, float* __restrict__ out, int n){
  int tid = threadIdx.x;
  int lr = tid & 15;
  int i = blockIdx.x*16 + (tid >> 4);
  if (i >= n) return;
  int p0 = offs[i], e = deg[i];
  float ax=0.f, ay=0.f, az=0.f;
  for (int q=lr; q<e; q+=16){
    int s = srcS[p0+q];
    float4 ws = wspin[s];
    ax += ws.x; ay += ws.y; az += ws.z;
  }
  #pragma unroll
  for (int m=1;m<16;m<<=1){
    ax += __shfl_xor(ax, m, 64);
    ay += __shfl_xor(ay, m, 64);
    az += __shfl_xor(az, m, 64);
  }
  if (lr == 0){
    out[(size_t)i*3+0] = ax;
    out[(size_t)i*3+1] = ay;
    out[(size_t)i*3+2] = az;
  }
}

extern "C" void kernel_launch(void* const* d_in, const int* in_sizes, int n_in,
                              void* d_out, int out_size, void* d_ws, size_t ws_size,
                              hipStream_t stream){
  const float* x      = (const float*)d_in[0];
  const int*   ei     = (const int*)  d_in[1];
  const float* eattr  = (const float*)d_in[2];
  const float* in_w   = (const float*)d_in[3];
  const float* in_b   = (const float*)d_in[4];
  const float* ew1    = (const float*)d_in[5];
  const float* eb1    = (const float*)d_in[6];
  const float* ew2    = (const float*)d_in[7];
  const float* eb2    = (const float*)d_in[8];
  const float* nw1    = (const float*)d_in[9];
  const float* nb1    = (const float*)d_in[10];
  const float* nw2    = (const float*)d_in[11];
  const float* nb2    = (const float*)d_in[12];
  const float* ow1    = (const float*)d_in[13];
  const float* ob1    = (const float*)d_in[14];
  const float* ow2    = (const float*)d_in[15];
  const float* ob2    = (const float*)d_in[16];
  float* out = (float*)d_out;

  const int N = in_sizes[0] / 5;
  const int E = in_sizes[1] / 2;

  char* w = (char*)d_ws;
  size_t off = 0;
  auto alloc = [&](size_t bytes)->size_t{
    size_t o = off; off = (off + bytes + 255) & ~(size_t)255; return o;
  };
  size_t o_flag   = alloc(4);
  size_t o_deg    = alloc((size_t)N*4);
  size_t o_offs   = alloc((size_t)N*4);
  size_t o_cursor = alloc((size_t)N*4);
  size_t o_bsum   = alloc(512*4);
  size_t o_nrec   = alloc((size_t)N*32);
  size_t o_wspin  = alloc((size_t)N*16);
  size_t o_h      = alloc((size_t)N*128*4);
  size_t o_A      = alloc((size_t)3*N*128*2);      // 3 layers, bf16
  size_t o_pew2   = alloc((size_t)3*128*128*2);
  size_t o_pnw1   = alloc((size_t)3*256*128*2);
  size_t o_pnw2   = alloc((size_t)3*128*128*2);
  size_t o_pow1   = alloc((size_t)128*128*2);
  size_t o_pew1   = alloc((size_t)3*4096*2);
  size_t o_srcS   = alloc((size_t)E*4);
  size_t o_scE    = alloc((size_t)E*32);
  if (off > ws_size) return;

  int*    flag   = (int*)   (w + o_flag);
  int*    deg    = (int*)   (w + o_deg);
  int*    offs   = (int*)   (w + o_offs);
  int*    cursor = (int*)   (w + o_cursor);
  int*    bsum   = (int*)   (w + o_bsum);
  float4* nrec   = (float4*)(w + o_nrec);
  float4* wspin  = (float4*)(w + o_wspin);
  float*  h      = (float*) (w + o_h);
  ushort* A      = (ushort*)(w + o_A);
  short*  p_ew2  = (short*) (w + o_pew2);
  short*  p_nw1  = (short*) (w + o_pnw1);
  short*  p_nw2  = (short*) (w + o_pnw2);
  short*  p_ow1  = (short*) (w + o_pow1);
  short*  p_ew1  = (short*) (w + o_pew1);
  int*    srcS   = (int*)   (w + o_srcS);
  ushort* scE    = (ushort*)(w + o_scE);

  (void)hipMemsetAsync(deg, 0, (size_t)N*4, stream);

  const int nb = (N + 255) / 256;
  const size_t lstride = (size_t)N*128;

  k_detect<<<1, 256, 0, stream>>>(ei, E, flag);
  k_deg<<<(E+255)/256, 256, 0, stream>>>(ei, E, flag, deg);
  k_scan1<<<nb, 256, 0, stream>>>(deg, offs, bsum, N);
  k_scan2<<<1, 512, 0, stream>>>(bsum, nb);
  k_scan3<<<nb, 256, 0, stream>>>(offs, bsum, cursor, N);
  k_node_pre<<<(N+1)/2, 256, 0, stream>>>(x, in_w, in_b, nrec, h, N);
  k_scatter<<<(E+255)/256, 256, 0, stream>>>(ei, E, flag, eattr, nrec, cursor, srcS, scE);
  k_pack<<<440, 64, 0, stream>>>(ew2, nw1, nw2, ow1, ew1, eb1,
                                 p_ew2, p_nw1, p_nw2, p_ow1, p_ew1);

  // all 3 layers' edge-hidden sums in ONE pass over sorted edges (16-edge groups)
  k_edge3<<<(N+3)/4, 256, 0, stream>>>(scE, offs, deg, p_ew1, A, N, lstride);

  const int gb = (N + 63) / 64;
  for (int l=0; l<2; ++l){
    k_layer<false><<<gb, 256, 0, stream>>>(A + lstride*l, h,
                                    p_ew2 + (size_t)l*16384, eb2 + (size_t)l*128,
                                    p_nw1 + (size_t)l*32768, nb1 + (size_t)l*128,
                                    p_nw2 + (size_t)l*16384, nb2 + (size_t)l*128,
                                    deg, nullptr, nullptr, nullptr, nullptr,
                                    nullptr, nullptr, N);
  }
  k_layer<true><<<gb, 256, 0, stream>>>(A + lstride*2, h,
                                  p_ew2 + (size_t)2*16384, eb2 + (size_t)2*128,
                                  p_nw1 + (size_t)2*32768, nb1 + (size_t)2*128,
                                  p_nw2 + (size_t)2*16384, nb2 + (size_t)2*128,
                                  deg, p_ow1, ob1, ow2, ob2,
                                  nrec, wspin, N);

  k_bfield<<<(N+15)/16, 256, 0, stream>>>(srcS, wspin, offs, deg, out, N);
}

// Round 14
// 857.737 us; speedup vs baseline: 1.0869x; 1.0117x over previous
//
#include <hip/hip_runtime.h>
#include <hip/hip_bf16.h>
#include <math.h>

typedef __attribute__((ext_vector_type(8))) short bf16x8;
typedef __attribute__((ext_vector_type(4))) float f32x4;
typedef __attribute__((ext_vector_type(4))) unsigned u32x4;

__device__ __forceinline__ float silu_f(float x){
  return x * __builtin_amdgcn_rcpf(1.f + __expf(-x));
}

// fp32 -> bf16 (round-to-nearest-even, finite inputs)
__device__ __forceinline__ short f2bs(float x){
  unsigned u = __builtin_bit_cast(unsigned, x);
  unsigned r = (u + 0x7fffu + ((u >> 16) & 1u)) >> 16;
  return (short)r;
}

// ---------------- edge-index layout detect (int64 vs int32) ----------------
__global__ void k_detect(const int* __restrict__ ei, int E, int* __restrict__ flag){
  __shared__ int nz;
  if (threadIdx.x==0) nz = 0;
  __syncthreads();
  int lim = E < 4096 ? E : 4096;
  int c = 0;
  for (int e = threadIdx.x; e < lim; e += blockDim.x)
    if (ei[2*e+1] != 0) c++;
  if (c) atomicAdd(&nz, c);
  __syncthreads();
  if (threadIdx.x==0) *flag = (nz==0) ? 1 : 0;   // 1 => int64 little-endian
}

__global__ __launch_bounds__(256) void k_deg(const int* __restrict__ ei, int E,
                                             const int* __restrict__ flag, int* __restrict__ deg){
  int e = blockIdx.x*blockDim.x + threadIdx.x;
  if (e >= E) return;
  int d = (*flag) ? ei[2*(E+e)] : ei[E+e];
  atomicAdd(&deg[d], 1);
}

// ---------------- exclusive scan over N (2-level) ----------------
__global__ __launch_bounds__(256) void k_scan1(const int* __restrict__ deg, int* __restrict__ offs,
                                               int* __restrict__ bsum, int n){
  __shared__ int sh[256];
  int i = blockIdx.x*256 + threadIdx.x;
  int v = (i < n) ? deg[i] : 0;
  sh[threadIdx.x] = v;
  __syncthreads();
  for (int off=1; off<256; off<<=1){
    int t = (threadIdx.x >= off) ? sh[threadIdx.x-off] : 0;
    __syncthreads();
    sh[threadIdx.x] += t;
    __syncthreads();
  }
  if (i < n) offs[i] = sh[threadIdx.x] - v;
  if (threadIdx.x == 255) bsum[blockIdx.x] = sh[255];
}

__global__ __launch_bounds__(512) void k_scan2(int* __restrict__ bsum, int nb){
  __shared__ int sh[512];
  int v = (threadIdx.x < nb) ? bsum[threadIdx.x] : 0;
  sh[threadIdx.x] = v;
  __syncthreads();
  for (int off=1; off<512; off<<=1){
    int t = (threadIdx.x >= off) ? sh[threadIdx.x-off] : 0;
    __syncthreads();
    sh[threadIdx.x] += t;
    __syncthreads();
  }
  if (threadIdx.x < nb) bsum[threadIdx.x] = sh[threadIdx.x] - v;
}

__global__ __launch_bounds__(256) void k_scan3(int* __restrict__ offs, const int* __restrict__ bsum,
                                               int* __restrict__ cursor, int n){
  int i = blockIdx.x*256 + threadIdx.x;
  if (i >= n) return;
  int o = offs[i] + bsum[i>>8];
  offs[i] = o;
  cursor[i] = o;
}

// ---------------- per-node precompute: nrec = {mx,my,mz,|m|, nt0,nt1,0,0}, h0 ----------------
__global__ __launch_bounds__(256) void k_node_pre(const float* __restrict__ x,
                                                  const float* __restrict__ inw, const float* __restrict__ inb,
                                                  float4* __restrict__ nrec,
                                                  float* __restrict__ h, int n){
  int half = threadIdx.x >> 7;
  int k = threadIdx.x & 127;
  int i = blockIdx.x*2 + half;
  if (i >= n) return;
  float nt0 = x[i*5+0], nt1 = x[i*5+1];
  float sx = x[i*5+2], sy = x[i*5+3], sz = x[i*5+4];
  float nrm = sqrtf(sx*sx + sy*sy + sz*sz);
  float d = fmaxf(nrm, 1e-12f);
  float mx = sx/d, my = sy/d, mz = sz/d;
  float rn = sqrtf(mx*mx + my*my + mz*mz);
  float v = nt0*inw[k] + nt1*inw[128+k] + rn*inw[256+k] + inb[k];
  h[i*128 + k] = silu_f(v);
  if (k == 0){
    nrec[(size_t)i*2]   = make_float4(mx, my, mz, rn);
    nrec[(size_t)i*2+1] = make_float4(nt0, nt1, 0.f, 0.f);
  }
}

// ---------------- scatter edges into dst-sorted order (32 B bf16 rows) ----------------
// scE row (16 bf16, 32 B): [|m_i|,|m_j|,mi·mj,mi·u,mj·u,dist,nti0,nti1,ntj0,ntj1, 1.0, 0...]
__global__ __launch_bounds__(256) void k_scatter(const int* __restrict__ ei, int E,
                                                 const int* __restrict__ flag,
                                                 const float* __restrict__ eattr,
                                                 const float4* __restrict__ nrec,
                                                 int* __restrict__ cursor,
                                                 int* __restrict__ srcS, ushort* __restrict__ scE){
  int e = blockIdx.x*blockDim.x + threadIdx.x;
  if (e >= E) return;
  int i64 = *flag;
  int s = i64 ? ei[2*e]       : ei[e];
  int d = i64 ? ei[2*(E+e)]   : ei[E+e];
  float4 ea = *(const float4*)(eattr + (size_t)e*4);
  float4 mi  = nrec[(size_t)d*2];
  float4 nti = nrec[(size_t)d*2+1];
  float4 mj  = nrec[(size_t)s*2];
  float4 ntj = nrec[(size_t)s*2+1];
  __align__(16) ushort row[16];
  row[0] = (ushort)f2bs(mi.w);
  row[1] = (ushort)f2bs(mj.w);
  row[2] = (ushort)f2bs(mi.x*mj.x + mi.y*mj.y + mi.z*mj.z);
  row[3] = (ushort)f2bs(mi.x*ea.x + mi.y*ea.y + mi.z*ea.z);
  row[4] = (ushort)f2bs(mj.x*ea.x + mj.y*ea.y + mj.z*ea.z);
  row[5] = (ushort)f2bs(ea.w);
  row[6] = (ushort)f2bs(nti.x);
  row[7] = (ushort)f2bs(nti.y);
  row[8] = (ushort)f2bs(ntj.x);
  row[9] = (ushort)f2bs(ntj.y);
  row[10]= 0x3F80;  // 1.0 bf16 (bias rides as B's k=10 row)
  row[11]=0; row[12]=0; row[13]=0; row[14]=0; row[15]=0;
  int pos = atomicAdd(&cursor[d], 1);
  srcS[pos] = s;
  u32x4* dstp = (u32x4*)(scE + (size_t)pos*16);
  dstp[0] = *(u32x4*)row;
  dstp[1] = *(u32x4*)(row + 8);
}

// ---------------- pack weights to MFMA B-fragment-major bf16 ----------------
// B-frag (16x16x32): lane L holds B[k=(L>>4)*8+e][n=L&15]; tile index = c*8+t
// blocks 416..439: ew1 (10x128, +bias row k=10, zero-pad to K=32)
__global__ __launch_bounds__(64) void k_pack(const float* __restrict__ ew2, const float* __restrict__ nw1,
                                             const float* __restrict__ nw2, const float* __restrict__ ow1,
                                             const float* __restrict__ ew1, const float* __restrict__ eb1,
                                             short* __restrict__ p_ew2, short* __restrict__ p_nw1,
                                             short* __restrict__ p_nw2, short* __restrict__ p_ow1,
                                             short* __restrict__ p_ew1){
  int b = blockIdx.x;
  int L = threadIdx.x;
  if (b >= 416){
    int tile = b - 416;          // 0..23
    int l = tile >> 3, t = tile & 7;
    int col = t*16 + (L & 15);
    int kb  = (L >> 4) << 3;
    __align__(16) short tmp[8];
    #pragma unroll
    for (int e=0;e<8;e++){
      int k = kb + e;
      float v = 0.f;
      if (k < 10)       v = ew1[(size_t)l*1280 + (size_t)k*128 + col];
      else if (k == 10) v = eb1[(size_t)l*128 + col];
      tmp[e] = f2bs(v);
    }
    *(bf16x8*)(p_ew1 + (size_t)l*4096 + t*512 + L*8) = *(bf16x8*)tmp;
    return;
  }
  const float* src; short* dst; int tile;
  if (b < 96){        int l = b>>5;              tile = b & 31; src = ew2 + (size_t)l*16384; dst = p_ew2 + (size_t)l*16384; }
  else if (b < 288){  int l = (b-96)>>6;         tile = (b-96) & 63; src = nw1 + (size_t)l*32768; dst = p_nw1 + (size_t)l*32768; }
  else if (b < 384){  int l = (b-288)>>5;        tile = (b-288) & 31; src = nw2 + (size_t)l*16384; dst = p_nw2 + (size_t)l*16384; }
  else {                                          tile = b - 384; src = ow1; dst = p_ow1; }
  int c = tile >> 3, t = tile & 7;
  int kb  = c*32 + ((L>>4)<<3);
  int col = t*16 + (L&15);
  __align__(16) short tmp[8];
  #pragma unroll
  for (int e=0;e<8;e++) tmp[e] = f2bs(src[(size_t)(kb+e)*128 + col]);
  *(bf16x8*)(dst + ((size_t)tile*64 + L)*8) = *(bf16x8*)tmp;
}

// ---------------- edge MLP hidden sums, ALL 3 layers, one kernel (wave per node) ----------------
// Three sequential per-layer passes (#pragma unroll 1) so only 8 B-frags + 8 accumulators
// are live at once -> low unified VGPR/AGPR pressure -> high occupancy.
// Wave re-reads its own ~deg*32B of scE per pass (L1-hot).
// 16-edge groups via 16x16x32; padded edges -> zero A-row -> silu(0)=0 -> no masking.
__global__ __launch_bounds__(256) void k_edge3(
    const ushort* __restrict__ scE,
    const int* __restrict__ offs, const int* __restrict__ deg,
    const short* __restrict__ p_ew1,
    ushort* __restrict__ A, int n, size_t lstride){
  int wv = threadIdx.x >> 6, lane = threadIdx.x & 63;
  int i = blockIdx.x*4 + wv;
  if (i >= n) return;
  int quad = lane >> 4, lr = lane & 15;
  int p0 = __builtin_amdgcn_readfirstlane(offs[i]);
  int dg = __builtin_amdgcn_readfirstlane(deg[i]);
  const f32x4 zf = {0.f,0.f,0.f,0.f};
  const u32x4 z4 = {0u,0u,0u,0u};
  #pragma unroll 1
  for (int l=0; l<3; ++l){
    float s8[8];
    #pragma unroll
    for (int t=0;t<8;t++) s8[t] = 0.f;
    const short* pB = p_ew1 + (size_t)l*4096 + (size_t)lane*8;
    for (int g=0; g<dg; g+=16){
      int e = g + lr;
      u32x4 d4 = z4;
      if (quad < 2 && e < dg)
        d4 = *(const u32x4*)(scE + ((size_t)(p0+e))*16 + quad*8);
      bf16x8 af = __builtin_bit_cast(bf16x8, d4);
      #pragma unroll
      for (int t=0;t<8;t++){
        bf16x8 bf = *(const bf16x8*)(pB + t*512);
        f32x4 acc = __builtin_amdgcn_mfma_f32_16x16x32_bf16(af, bf, zf, 0, 0, 0);
        s8[t] += silu_f(acc[0]) + silu_f(acc[1]) + silu_f(acc[2]) + silu_f(acc[3]);
      }
    }
    #pragma unroll
    for (int t=0;t<8;t++){
      s8[t] += __shfl_xor(s8[t], 16, 64);
      s8[t] += __shfl_xor(s8[t], 32, 64);
    }
    if (quad == 0){
      #pragma unroll
      for (int t=0;t<8;t++)
        A[lstride*l + (size_t)i*128 + t*16 + lr] = (ushort)f2bs(s8[t]);
    }
  }
}

// ---------------- MFMA wave GEMM: 16 rows x 128 cols, K = kchunks*32 ----------------
__device__ __forceinline__ void wave_gemm(const short* __restrict__ sIn, const short* __restrict__ pw,
                                          int lane, int kchunks, f32x4 acc[8]){
  for (int c=0;c<kchunks;c++){
    bf16x8 af = *(const bf16x8*)(sIn + (lane&15)*136 + c*32 + ((lane>>4)<<3));
    const short* pB = pw + (size_t)c*4096 + (size_t)lane*8;
    #pragma unroll
    for (int t=0;t<8;t++){
      bf16x8 bf = *(const bf16x8*)(pB + t*512);
      acc[t] = __builtin_amdgcn_mfma_f32_16x16x32_bf16(af, bf, acc[t], 0, 0, 0);
    }
  }
}

// ---------------- fused per-layer node update (MFMA); LAST also computes head + wspin ----------------
template<bool LAST>
__global__ __launch_bounds__(256) void k_layer(
    const ushort* __restrict__ A, float* __restrict__ h,
    const short* __restrict__ p_ew2, const float* __restrict__ eb2,
    const short* __restrict__ p_nw1, const float* __restrict__ nb1,
    const short* __restrict__ p_nw2, const float* __restrict__ nb2,
    const int* __restrict__ deg,
    const short* __restrict__ p_ow1, const float* __restrict__ ob1,
    const float* __restrict__ ow2, const float* __restrict__ ob2,
    const float4* __restrict__ nrec, float4* __restrict__ wspin, int n){
  __shared__ __align__(16) short sA[64*136];
  __shared__ __align__(16) short sH[64*136];
  __shared__ __align__(16) short sG[64*136];
  int tid = threadIdx.x;
  int lane = tid & 63, wave = tid >> 6;
  int row0 = blockIdx.x*64;

  #pragma unroll
  for (int q=0;q<8;q++){
    int id = tid + q*256;
    int r = id >> 5;
    int cq = (id & 31) << 2;
    int row = row0 + r;
    ushort4 va = make_ushort4(0,0,0,0);
    float4 vh = make_float4(0.f,0.f,0.f,0.f);
    if (row < n){
      va = *(const ushort4*)(A + (size_t)row*128 + cq);
      vh = *(const float4*)(h + (size_t)row*128 + cq);
    }
    *(ushort4*)&sA[r*136 + cq] = va;
    short4 hs; hs.x = f2bs(vh.x); hs.y = f2bs(vh.y); hs.z = f2bs(vh.z); hs.w = f2bs(vh.w);
    *(short4*)&sH[r*136 + cq] = hs;
  }
  __syncthreads();

  const short* sInA = sA + wave*16*136;
  const short* sInH = sH + wave*16*136;
  const short* sInG = sG + wave*16*136;
  int lr = lane & 15;
  int rbase = wave*16 + ((lane>>4)<<2);

  f32x4 acc[8];
  const f32x4 zf = {0.f,0.f,0.f,0.f};

  // GEMM-A: aggr = A @ ew2 + deg*eb2 -> sG
  #pragma unroll
  for (int t=0;t<8;t++) acc[t] = zf;
  wave_gemm(sInA, p_ew2, lane, 4, acc);
  {
    float dd[4];
    #pragma unroll
    for (int r=0;r<4;r++){
      int row = row0 + rbase + r;
      dd[r] = (row < n) ? (float)deg[row] : 0.f;
    }
    #pragma unroll
    for (int t=0;t<8;t++){
      int col = t*16 + lr;
      float bv = eb2[col];
      #pragma unroll
      for (int r=0;r<4;r++)
        sG[(rbase+r)*136 + col] = f2bs(acc[t][r] + dd[r]*bv);
    }
  }
  __syncthreads();

  // GEMM-B: u = silu([h|aggr] @ nw1 + nb1) -> sA
  #pragma unroll
  for (int t=0;t<8;t++) acc[t] = zf;
  wave_gemm(sInH, p_nw1,         lane, 4, acc);
  wave_gemm(sInG, p_nw1 + 16384, lane, 4, acc);
  __syncthreads();
  {
    #pragma unroll
    for (int t=0;t<8;t++){
      int col = t*16 + lr;
      float bv = nb1[col];
      #pragma unroll
      for (int r=0;r<4;r++)
        sA[(rbase+r)*136 + col] = f2bs(silu_f(acc[t][r] + bv));
    }
  }
  __syncthreads();

  // GEMM-C: h_new = h + u @ nw2 + nb2
  #pragma unroll
  for (int t=0;t<8;t++) acc[t] = zf;
  wave_gemm(sInA, p_nw2, lane, 4, acc);
  {
    #pragma unroll
    for (int t=0;t<8;t++){
      int col = t*16 + lr;
      float bv = nb2[col];
      #pragma unroll
      for (int r=0;r<4;r++){
        int row = row0 + rbase + r;
        if (row < n){
          size_t idx = (size_t)row*128 + col;
          float hv = h[idx] + acc[t][r] + bv;
          if (LAST) sH[(rbase+r)*136 + col] = f2bs(hv);  // wave-private stripe
          else      h[idx] = hv;
        }
      }
    }
  }

  if (LAST){
    // head: w = silu(h_new@ow1+ob1)·ow2 + ob2 ; wspin[row] = w * spin[row]
    #pragma unroll
    for (int t=0;t<8;t++) acc[t] = zf;
    wave_gemm(sInH, p_ow1, lane, 4, acc);
    float p[4] = {0.f,0.f,0.f,0.f};
    #pragma unroll
    for (int t=0;t<8;t++){
      int col = t*16 + lr;
      float b1 = ob1[col], w2 = ow2[col];
      #pragma unroll
      for (int r=0;r<4;r++) p[r] += silu_f(acc[t][r] + b1)*w2;
    }
    #pragma unroll
    for (int m=1;m<16;m<<=1){
      #pragma unroll
      for (int r=0;r<4;r++) p[r] += __shfl_xor(p[r], m, 64);
    }
    if (lr == 0){
      float b = ob2[0];
      #pragma unroll
      for (int r=0;r<4;r++){
        int row = row0 + rbase + r;
        if (row < n){
          float wv = p[r] + b;
          float4 sp = nrec[(size_t)row*2];
          wspin[row] = make_float4(wv*sp.x, wv*sp.y, wv*sp.z, 0.f);
        }
      }
    }
  }
}

// ---------------- b_field: quad (16 lanes) per node, single wspin gather ----------------
__global__ __launch_bounds__(256) void k_bfield(const int* __restrict__ srcS,
                                                const float4* __restrict__ wspin,
                                                const int* __restrict__ offs,
                                                const int* __restrict__ deg, float* __restrict__ out, int n){
  int tid = threadIdx.x;
  int lr = tid & 15;
  int i = blockIdx.x*16 + (tid >> 4);
  if (i >= n) return;
  int p0 = offs[i], e = deg[i];
  float ax=0.f, ay=0.f, az=0.f;
  for (int q=lr; q<e; q+=16){
    int s = srcS[p0+q];
    float4 ws = wspin[s];
    ax += ws.x; ay += ws.y; az += ws.z;
  }
  #pragma unroll
  for (int m=1;m<16;m<<=1){
    ax += __shfl_xor(ax, m, 64);
    ay += __shfl_xor(ay, m, 64);
    az += __shfl_xor(az, m, 64);
  }
  if (lr == 0){
    out[(size_t)i*3+0] = ax;
    out[(size_t)i*3+1] = ay;
    out[(size_t)i*3+2] = az;
  }
}

extern "C" void kernel_launch(void* const* d_in, const int* in_sizes, int n_in,
                              void* d_out, int out_size, void* d_ws, size_t ws_size,
                              hipStream_t stream){
  const float* x      = (const float*)d_in[0];
  const int*   ei     = (const int*)  d_in[1];
  const float* eattr  = (const float*)d_in[2];
  const float* in_w   = (const float*)d_in[3];
  const float* in_b   = (const float*)d_in[4];
  const float* ew1    = (const float*)d_in[5];
  const float* eb1    = (const float*)d_in[6];
  const float* ew2    = (const float*)d_in[7];
  const float* eb2    = (const float*)d_in[8];
  const float* nw1    = (const float*)d_in[9];
  const float* nb1    = (const float*)d_in[10];
  const float* nw2    = (const float*)d_in[11];
  const float* nb2    = (const float*)d_in[12];
  const float* ow1    = (const float*)d_in[13];
  const float* ob1    = (const float*)d_in[14];
  const float* ow2    = (const float*)d_in[15];
  const float* ob2    = (const float*)d_in[16];
  float* out = (float*)d_out;

  const int N = in_sizes[0] / 5;
  const int E = in_sizes[1] / 2;

  char* w = (char*)d_ws;
  size_t off = 0;
  auto alloc = [&](size_t bytes)->size_t{
    size_t o = off; off = (off + bytes + 255) & ~(size_t)255; return o;
  };
  size_t o_flag   = alloc(4);
  size_t o_deg    = alloc((size_t)N*4);
  size_t o_offs   = alloc((size_t)N*4);
  size_t o_cursor = alloc((size_t)N*4);
  size_t o_bsum   = alloc(512*4);
  size_t o_nrec   = alloc((size_t)N*32);
  size_t o_wspin  = alloc((size_t)N*16);
  size_t o_h      = alloc((size_t)N*128*4);
  size_t o_A      = alloc((size_t)3*N*128*2);      // 3 layers, bf16
  size_t o_pew2   = alloc((size_t)3*128*128*2);
  size_t o_pnw1   = alloc((size_t)3*256*128*2);
  size_t o_pnw2   = alloc((size_t)3*128*128*2);
  size_t o_pow1   = alloc((size_t)128*128*2);
  size_t o_pew1   = alloc((size_t)3*4096*2);
  size_t o_srcS   = alloc((size_t)E*4);
  size_t o_scE    = alloc((size_t)E*32);
  if (off > ws_size) return;

  int*    flag   = (int*)   (w + o_flag);
  int*    deg    = (int*)   (w + o_deg);
  int*    offs   = (int*)   (w + o_offs);
  int*    cursor = (int*)   (w + o_cursor);
  int*    bsum   = (int*)   (w + o_bsum);
  float4* nrec   = (float4*)(w + o_nrec);
  float4* wspin  = (float4*)(w + o_wspin);
  float*  h      = (float*) (w + o_h);
  ushort* A      = (ushort*)(w + o_A);
  short*  p_ew2  = (short*) (w + o_pew2);
  short*  p_nw1  = (short*) (w + o_pnw1);
  short*  p_nw2  = (short*) (w + o_pnw2);
  short*  p_ow1  = (short*) (w + o_pow1);
  short*  p_ew1  = (short*) (w + o_pew1);
  int*    srcS   = (int*)   (w + o_srcS);
  ushort* scE    = (ushort*)(w + o_scE);

  (void)hipMemsetAsync(deg, 0, (size_t)N*4, stream);

  const int nb = (N + 255) / 256;
  const size_t lstride = (size_t)N*128;

  k_detect<<<1, 256, 0, stream>>>(ei, E, flag);
  k_deg<<<(E+255)/256, 256, 0, stream>>>(ei, E, flag, deg);
  k_scan1<<<nb, 256, 0, stream>>>(deg, offs, bsum, N);
  k_scan2<<<1, 512, 0, stream>>>(bsum, nb);
  k_scan3<<<nb, 256, 0, stream>>>(offs, bsum, cursor, N);
  k_node_pre<<<(N+1)/2, 256, 0, stream>>>(x, in_w, in_b, nrec, h, N);
  k_scatter<<<(E+255)/256, 256, 0, stream>>>(ei, E, flag, eattr, nrec, cursor, srcS, scE);
  k_pack<<<440, 64, 0, stream>>>(ew2, nw1, nw2, ow1, ew1, eb1,
                                 p_ew2, p_nw1, p_nw2, p_ow1, p_ew1);

  // all 3 layers' edge-hidden sums: one kernel, three low-pressure passes
  k_edge3<<<(N+3)/4, 256, 0, stream>>>(scE, offs, deg, p_ew1, A, N, lstride);

  const int gb = (N + 63) / 64;
  for (int l=0; l<2; ++l){
    k_layer<false><<<gb, 256, 0, stream>>>(A + lstride*l, h,
                                    p_ew2 + (size_t)l*16384, eb2 + (size_t)l*128,
                                    p_nw1 + (size_t)l*32768, nb1 + (size_t)l*128,
                                    p_nw2 + (size_t)l*16384, nb2 + (size_t)l*128,
                                    deg, nullptr, nullptr, nullptr, nullptr,
                                    nullptr, nullptr, N);
  }
  k_layer<true><<<gb, 256, 0, stream>>>(A + lstride*2, h,
                                  p_ew2 + (size_t)2*16384, eb2 + (size_t)2*128,
                                  p_nw1 + (size_t)2*32768, nb1 + (size_t)2*128,
                                  p_nw2 + (size_t)2*16384, nb2 + (size_t)2*128,
                                  deg, p_ow1, ob1, ow2, ob2,
                                  nrec, wspin, N);

  k_bfield<<<(N+15)/16, 256, 0, stream>>>(srcS, wspin, offs, deg, out, N);
}